// Round 3
// baseline (168.101 us; speedup 1.0000x reference)
//
#include <hip/hip_runtime.h>
#include <hip/hip_bf16.h>

// ARAPLoss: out[b] = mean_e | ||x[b,dst]-x[b,src]||^2 - ||dx[b,dst]-dx[b,src]||^2 |
// B=8, NV=100000, E ~ 1.19M directed dedup edges (sorted by src).
//
// R1: batch-inner loop -> 19.2MB/XCD working set -> L2 thrash, 1.03GB fetch, 345us.
// R2: pack + batch-per-XCD (blockIdx&7) -> fetch 54MB, main 66us, but pack
//     pre-pass + extra launch cost ~79us of the 145us total.
// R3: drop pack (unpacked per-batch slice = 2.4MB < 4MiB L2; dwordx3 gathers),
//     2-edge unroll for gather ILP (main kernel is L2-latency bound: VALU 10%,
//     HBM 10%, ~18 serial gather iterations/thread).

#define NBATCH 8
#define NVERT 100000

__global__ __launch_bounds__(256) void arap_edge_direct_kernel(
    const float* __restrict__ dx, const float* __restrict__ x,
    const int* __restrict__ src, const int* __restrict__ dst,
    float* __restrict__ out, int E, float invE)
{
    const int b = blockIdx.x & 7;          // batch == XCD (round-robin dispatch)
    const int chunk = blockIdx.x >> 3;
    const int nchunk = gridDim.x >> 3;
    const int stride = nchunk * blockDim.x;

    const float* __restrict__ xb  = x  + (size_t)b * NVERT * 3;
    const float* __restrict__ dxb = dx + (size_t)b * NVERT * 3;

    float acc = 0.0f;
    int e = chunk * blockDim.x + threadIdx.x;

    // 2-edge unroll: two independent gather chains in flight per thread
    for (; e + stride < E; e += 2 * stride) {
        const int e1 = e + stride;
        const int s0 = src[e] * 3,  d0 = dst[e] * 3;
        const int s1 = src[e1] * 3, d1 = dst[e1] * 3;

        float ax0 = xb[d0]   - xb[s0];
        float ax1 = xb[d0+1] - xb[s0+1];
        float ax2 = xb[d0+2] - xb[s0+2];
        float ad0 = dxb[d0]   - dxb[s0];
        float ad1 = dxb[d0+1] - dxb[s0+1];
        float ad2 = dxb[d0+2] - dxb[s0+2];

        float bx0 = xb[d1]   - xb[s1];
        float bx1 = xb[d1+1] - xb[s1+1];
        float bx2 = xb[d1+2] - xb[s1+2];
        float bd0 = dxb[d1]   - dxb[s1];
        float bd1 = dxb[d1+1] - dxb[s1+1];
        float bd2 = dxb[d1+2] - dxb[s1+2];

        acc += fabsf(ax0*ax0 + ax1*ax1 + ax2*ax2 - (ad0*ad0 + ad1*ad1 + ad2*ad2));
        acc += fabsf(bx0*bx0 + bx1*bx1 + bx2*bx2 - (bd0*bd0 + bd1*bd1 + bd2*bd2));
    }
    if (e < E) {
        const int s0 = src[e] * 3, d0 = dst[e] * 3;
        float ax0 = xb[d0]   - xb[s0];
        float ax1 = xb[d0+1] - xb[s0+1];
        float ax2 = xb[d0+2] - xb[s0+2];
        float ad0 = dxb[d0]   - dxb[s0];
        float ad1 = dxb[d0+1] - dxb[s0+1];
        float ad2 = dxb[d0+2] - dxb[s0+2];
        acc += fabsf(ax0*ax0 + ax1*ax1 + ax2*ax2 - (ad0*ad0 + ad1*ad1 + ad2*ad2));
    }

    // 64-lane wave reduction
#pragma unroll
    for (int off = 32; off > 0; off >>= 1)
        acc += __shfl_down(acc, off, 64);

    __shared__ float red[4];
    const int wave = threadIdx.x >> 6;
    const int lane = threadIdx.x & 63;
    if (lane == 0) red[wave] = acc;
    __syncthreads();
    if (threadIdx.x == 0) {
        float t = red[0] + red[1] + red[2] + red[3];
        atomicAdd(&out[b], t * invE);
    }
}

extern "C" void kernel_launch(void* const* d_in, const int* in_sizes, int n_in,
                              void* d_out, int out_size, void* d_ws, size_t ws_size,
                              hipStream_t stream) {
    const float* dx = (const float*)d_in[0];
    const float* x  = (const float*)d_in[1];
    const int* edge_src = (const int*)d_in[2];
    const int* edge_dst = (const int*)d_in[3];
    float* out = (float*)d_out;

    const int E = in_sizes[2];
    const float invE = 1.0f / (float)E;

    hipMemsetAsync(d_out, 0, NBATCH * sizeof(float), stream);

    // 2048 blocks = 8 blocks/CU (32 waves, full residency); batch = blockIdx&7
    // keeps each batch's 2.4MB (x+dx) slice resident in one XCD's 4MiB L2.
    arap_edge_direct_kernel<<<2048, 256, 0, stream>>>(dx, x, edge_src, edge_dst,
                                                      out, E, invE);
}